// Round 1
// baseline (911.969 us; speedup 1.0000x reference)
//
#include <hip/hip_runtime.h>
#include <cstdint>

// PiNet: B=8192, I=12, O=512, DEG=4.
// out[b,o] = w0[o] + sum_d w_d[o,:] . (x_b tensor-power d)
// Symmetry-folded: only multisets {j<=k<=l<=m} matter ->
// T = 1 + 12 + 78 + 364 + 1365 = 1820 distinct monomials (vs 22621).

#define NB 8192
#define NI 12
#define NO 512
#define T_TOTAL 1820
#define TPAD 1824           // pad to multiple of KT
#define B2 13               // base of degree-2 block in t-space
#define B3 91               // base of degree-3 block
#define B4 455              // base of degree-4 block

// ---------- combinatorial rank helpers (lex order over sorted tuples) ----------
__device__ __forceinline__ int H2f(int n) { return n * (n + 1) / 2; }
__device__ __forceinline__ int H3f(int n) { return n * (n + 1) * (n + 2) / 6; }

__device__ __forceinline__ int rank2(int a, int b) {
    int r = 0;
    for (int j = 0; j < a; ++j) r += NI - j;
    return r + (b - a);
}
__device__ __forceinline__ int rank3(int a, int b, int c) {
    int r = 0;
    for (int j = 0; j < a; ++j) r += H2f(NI - j);
    for (int k = a; k < b; ++k) r += NI - k;
    return r + (c - b);
}
__device__ __forceinline__ int rank4(int a, int b, int c, int d) {
    int r = 0;
    for (int j = 0; j < a; ++j) r += H3f(NI - j);
    for (int k = a; k < b; ++k) r += H2f(NI - k);
    for (int l = b; l < c; ++l) r += NI - l;
    return r + (d - c);
}

__device__ __forceinline__ void cswap(int& a, int& b) {
    if (a > b) { int t = a; a = b; b = t; }
}

// ---------- kernel B: build monomial index table ----------
// mono[t] = packed bytes (i0,i1,i2,i3), index 12 means "multiply by 1".
// Pre-filled with 0x0C (=(12,12,12,12)) by memset: covers t=0 and padding.
__global__ __launch_bounds__(256) void pinet_mono(uint32_t* __restrict__ mono) {
    int i = blockIdx.x * 256 + threadIdx.x;
    if (i < 20736) {
        int a = i / 1728, r = i % 1728;
        int b = r / 144;  r = r % 144;
        int c = r / 12,  d = r % 12;
        if (a <= b && b <= c && c <= d)
            mono[B4 + rank4(a, b, c, d)] =
                (uint32_t)a | ((uint32_t)b << 8) | ((uint32_t)c << 16) | ((uint32_t)d << 24);
        return;
    }
    i -= 20736;
    if (i < 1728) {
        int a = i / 144, r = i % 144;
        int b = r / 12, c = r % 12;
        if (a <= b && b <= c)
            mono[B3 + rank3(a, b, c)] =
                (uint32_t)a | ((uint32_t)b << 8) | ((uint32_t)c << 16) | (12u << 24);
        return;
    }
    i -= 1728;
    if (i < 144) {
        int a = i / 12, b = i % 12;
        if (a <= b)
            mono[B2 + rank2(a, b)] =
                (uint32_t)a | ((uint32_t)b << 8) | (12u << 16) | (12u << 24);
        return;
    }
    i -= 144;
    if (i < 12) {
        mono[1 + i] = (uint32_t)i | (12u << 8) | (12u << 16) | (12u << 24);
    }
    // t=0 stays (12,12,12,12) from the 0x0C memset.
}

// ---------- fold kernel: Wt[t][o] = sum over permutation orbit of w_d ----------
// One thread per source element; flat id over (w0|w1|w2|w3|w4). Reads coalesced.
// Wt layout: [TPAD][512] row-major. Wt zeroed beforehand.
#define N0 512
#define N1 6144        // 512*12
#define N2 73728       // 512*144
#define N3 884736      // 512*1728
#define N4 10616832    // 512*20736
#define NFOLD (N0 + N1 + N2 + N3 + N4)   // 11,581,952 = 45242*256

__global__ __launch_bounds__(256) void pinet_fold(
    const float* __restrict__ w0, const float* __restrict__ w1,
    const float* __restrict__ w2, const float* __restrict__ w3,
    const float* __restrict__ w4, float* __restrict__ Wt) {
    int i = blockIdx.x * 256 + threadIdx.x;
    if (i < N0) { Wt[i] = w0[i]; return; }                  // t=0 row
    i -= N0;
    if (i < N1) {                                           // degree 1: unique
        int o = i / 12, j = i % 12;
        Wt[(1 + j) * NO + o] = w1[i];
        return;
    }
    i -= N1;
    if (i < N2) {                                           // degree 2
        int o = i / 144, c = i % 144;
        int a = c / 12, b = c % 12;
        cswap(a, b);
        atomicAdd(&Wt[(B2 + rank2(a, b)) * NO + o], w2[i]);
        return;
    }
    i -= N2;
    if (i < N3) {                                           // degree 3
        int o = i / 1728, c = i % 1728;
        int a = c / 144, r = c % 144;
        int b = r / 12, cc = r % 12;
        cswap(a, b); cswap(a, cc); cswap(b, cc);
        atomicAdd(&Wt[(B3 + rank3(a, b, cc)) * NO + o], w3[i]);
        return;
    }
    i -= N3;
    if (i < N4) {                                           // degree 4
        int o = i / 20736, c = i % 20736;
        int a = c / 1728, r = c % 1728;
        int b = r / 144;  r = r % 144;
        int cc = r / 12,  d = r % 12;
        cswap(a, b); cswap(cc, d); cswap(a, cc); cswap(b, d); cswap(b, cc);
        atomicAdd(&Wt[(B4 + rank4(a, b, cc, d)) * NO + o], w4[i]);
    }
}

// ---------- main GEMM: out[b,o] = sum_t Wt[t][o] * M[t][b] ----------
// M generated on the fly from x. Tile: 128 b x 64 o, 256 threads,
// per-thread 8(o) x 4(b) fp32 accumulator. K-tile = 32.
#define BB 128
#define OO 64
#define KT 32
#define NKT (TPAD / KT)   // 57

__global__ __launch_bounds__(256) void pinet_gemm(
    const float* __restrict__ x,        // [8192, 12]
    const float* __restrict__ Wt,       // [TPAD][512]
    const uint32_t* __restrict__ mono,  // [TPAD]
    float* __restrict__ out) {          // [8192, 512]
    __shared__ float xsh[BB][13];       // x tile + implicit 1.0 at idx 12
    __shared__ float Wsh[KT][OO];
    __shared__ float Msh[KT][BB];

    const int tid = threadIdx.x;
    const int bx = blockIdx.x & 63;     // b-tile (64)
    const int by = blockIdx.x >> 6;     // o-tile (8)
    const int b0 = bx * BB, o0 = by * OO;

    // stage x tile (coalesced) + constant-1 column
    for (int idx = tid; idx < BB * 12; idx += 256) {
        int b = idx / 12, j = idx % 12;
        xsh[b][j] = x[(b0 + b) * 12 + j];
    }
    if (tid < BB) xsh[tid][12] = 1.0f;

    float acc[8][4];
#pragma unroll
    for (int i = 0; i < 8; ++i)
#pragma unroll
        for (int j = 0; j < 4; ++j) acc[i][j] = 0.0f;

    const int to = tid & 7;    // 8 groups over o (8 o each)
    const int tb = tid >> 3;   // 32 groups over b (4 b each)

    for (int kt = 0; kt < NKT; ++kt) {
        __syncthreads();
        // stage Wsh: 32x64 floats, wave reads contiguous 256B rows
#pragma unroll
        for (int r = 0; r < 8; ++r) {
            int idx = r * 256 + tid;
            int k = idx >> 6, o = idx & 63;
            Wsh[k][o] = Wt[(kt * KT + k) * NO + o0 + o];
        }
        // stage Msh: 32x128 monomials, computed from xsh
#pragma unroll
        for (int r = 0; r < 16; ++r) {
            int idx = r * 256 + tid;
            int k = idx >> 7, b = idx & 127;
            uint32_t u = mono[kt * KT + k];
            float v = xsh[b][u & 15] * xsh[b][(u >> 8) & 15] *
                      xsh[b][(u >> 16) & 15] * xsh[b][(u >> 24) & 15];
            Msh[k][b] = v;
        }
        __syncthreads();
#pragma unroll
        for (int k = 0; k < KT; ++k) {
            float4 wa = *(const float4*)&Wsh[k][to * 8];
            float4 wb = *(const float4*)&Wsh[k][to * 8 + 4];
            float4 mv = *(const float4*)&Msh[k][tb * 4];
            float wv[8] = {wa.x, wa.y, wa.z, wa.w, wb.x, wb.y, wb.z, wb.w};
            float mm[4] = {mv.x, mv.y, mv.z, mv.w};
#pragma unroll
            for (int i = 0; i < 8; ++i)
#pragma unroll
                for (int j = 0; j < 4; ++j)
                    acc[i][j] = fmaf(wv[i], mm[j], acc[i][j]);
        }
    }

    // write out[b][o], two float4 per (thread, b)
#pragma unroll
    for (int j = 0; j < 4; ++j) {
        int b = b0 + tb * 4 + j;
        float4 v0 = {acc[0][j], acc[1][j], acc[2][j], acc[3][j]};
        float4 v1 = {acc[4][j], acc[5][j], acc[6][j], acc[7][j]};
        *(float4*)&out[b * NO + o0 + to * 8] = v0;
        *(float4*)&out[b * NO + o0 + to * 8 + 4] = v1;
    }
}

extern "C" void kernel_launch(void* const* d_in, const int* in_sizes, int n_in,
                              void* d_out, int out_size, void* d_ws, size_t ws_size,
                              hipStream_t stream) {
    const float* x  = (const float*)d_in[0];
    const float* w0 = (const float*)d_in[1];
    const float* w1 = (const float*)d_in[2];
    const float* w2 = (const float*)d_in[3];
    const float* w3 = (const float*)d_in[4];
    const float* w4 = (const float*)d_in[5];
    float* out = (float*)d_out;

    uint8_t* ws = (uint8_t*)d_ws;
    uint32_t* mono = (uint32_t*)ws;                 // TPAD u32 = 7296 B
    float* Wt = (float*)(ws + 8192);                // [TPAD][512] = 3.74 MB

    // mono pre-fill: every byte 0x0C -> (12,12,12,12) = constant monomial
    hipMemsetAsync(mono, 0x0C, TPAD * sizeof(uint32_t), stream);
    hipMemsetAsync(Wt, 0, TPAD * NO * sizeof(float), stream);

    pinet_mono<<<(22620 + 255) / 256, 256, 0, stream>>>(mono);
    pinet_fold<<<NFOLD / 256, 256, 0, stream>>>(w0, w1, w2, w3, w4, Wt);
    pinet_gemm<<<(NB / BB) * (NO / OO), 256, 0, stream>>>(x, Wt, mono, out);
}

// Round 2
// 388.383 us; speedup vs baseline: 2.3481x; 2.3481x over previous
//
#include <hip/hip_runtime.h>
#include <cstdint>

// PiNet: B=8192, I=12, O=512, DEG=4.
// out[b,o] = w0[o] + sum_d w_d[o,:] . (x_b tensor-power d)
// Symmetry-folded: T = 1 + 12 + 78 + 364 + 1365 = 1820 distinct monomials.
// R1: atomic scatter-fold replaced by deterministic orbit-table gather-fold.

#define NB 8192
#define NI 12
#define NO 512
#define T_TOTAL 1820
#define TPAD 1824
#define B2 13
#define B3 91
#define B4 455

__device__ __forceinline__ int H2f(int n) { return n * (n + 1) / 2; }
__device__ __forceinline__ int H3f(int n) { return n * (n + 1) * (n + 2) / 6; }

__device__ __forceinline__ int rank2(int a, int b) {
    int r = 0;
    for (int j = 0; j < a; ++j) r += NI - j;
    return r + (b - a);
}
__device__ __forceinline__ int rank3(int a, int b, int c) {
    int r = 0;
    for (int j = 0; j < a; ++j) r += H2f(NI - j);
    for (int k = a; k < b; ++k) r += NI - k;
    return r + (c - b);
}
__device__ __forceinline__ int rank4(int a, int b, int c, int d) {
    int r = 0;
    for (int j = 0; j < a; ++j) r += H3f(NI - j);
    for (int k = a; k < b; ++k) r += H2f(NI - k);
    for (int l = b; l < c; ++l) r += NI - l;
    return r + (d - c);
}

// ---------- monomial index table (for GEMM on-the-fly features) ----------
// mono[t] = packed bytes (i0,i1,i2,i3), index 12 means "multiply by 1".
// Pre-filled with 0x0C (=(12,12,12,12)) by memset: covers t=0 and padding.
__global__ __launch_bounds__(256) void pinet_mono(uint32_t* __restrict__ mono) {
    int i = blockIdx.x * 256 + threadIdx.x;
    if (i < 20736) {
        int a = i / 1728, r = i % 1728;
        int b = r / 144;  r = r % 144;
        int c = r / 12,  d = r % 12;
        if (a <= b && b <= c && c <= d)
            mono[B4 + rank4(a, b, c, d)] =
                (uint32_t)a | ((uint32_t)b << 8) | ((uint32_t)c << 16) | ((uint32_t)d << 24);
        return;
    }
    i -= 20736;
    if (i < 1728) {
        int a = i / 144, r = i % 144;
        int b = r / 12, c = r % 12;
        if (a <= b && b <= c)
            mono[B3 + rank3(a, b, c)] =
                (uint32_t)a | ((uint32_t)b << 8) | ((uint32_t)c << 16) | (12u << 24);
        return;
    }
    i -= 1728;
    if (i < 144) {
        int a = i / 12, b = i % 12;
        if (a <= b)
            mono[B2 + rank2(a, b)] =
                (uint32_t)a | ((uint32_t)b << 8) | (12u << 16) | (12u << 24);
        return;
    }
    i -= 144;
    if (i < 12) {
        mono[1 + i] = (uint32_t)i | (12u << 8) | (12u << 16) | (12u << 24);
    }
}

// ---------- orbit tables: for each sorted tuple, the distinct source columns ----------
// Deterministic (fixed enumeration order, no atomics).
__global__ __launch_bounds__(256) void pinet_tables(
    uint32_t* __restrict__ cnt2, uint16_t* __restrict__ list2,
    uint32_t* __restrict__ cnt3, uint16_t* __restrict__ list3,
    uint32_t* __restrict__ cnt4, uint16_t* __restrict__ list4) {
    int t = blockIdx.x * 256 + threadIdx.x;
    if (t < 1365) {                       // degree 4
        int r = t;
        int a = 0; while (r >= H3f(NI - a)) { r -= H3f(NI - a); ++a; }
        int b = a; while (r >= H2f(NI - b)) { r -= H2f(NI - b); ++b; }
        int c = b; while (r >= (NI - c)) { r -= (NI - c); ++c; }
        int d = c + r;
        int vals[4] = {a, b, c, d};
        uint16_t cols[24]; int n = 0;
        for (int p0 = 0; p0 < 4; ++p0)
            for (int p1 = 0; p1 < 4; ++p1) {
                if (p1 == p0) continue;
                for (int p2 = 0; p2 < 4; ++p2) {
                    if (p2 == p0 || p2 == p1) continue;
                    int p3 = 6 - p0 - p1 - p2;
                    int col = vals[p0] * 1728 + vals[p1] * 144 + vals[p2] * 12 + vals[p3];
                    bool dup = false;
                    for (int j = 0; j < n; ++j) if (cols[j] == (uint16_t)col) { dup = true; break; }
                    if (!dup) cols[n++] = (uint16_t)col;
                }
            }
        cnt4[t] = n;
        for (int j = 0; j < n; ++j) list4[t * 24 + j] = cols[j];
        return;
    }
    t -= 1365;
    if (t < 364) {                        // degree 3
        int r = t;
        int a = 0; while (r >= H2f(NI - a)) { r -= H2f(NI - a); ++a; }
        int b = a; while (r >= (NI - b)) { r -= (NI - b); ++b; }
        int c = b + r;
        int vals[3] = {a, b, c};
        uint16_t cols[6]; int n = 0;
        for (int p0 = 0; p0 < 3; ++p0)
            for (int p1 = 0; p1 < 3; ++p1) {
                if (p1 == p0) continue;
                int p2 = 3 - p0 - p1;
                int col = vals[p0] * 144 + vals[p1] * 12 + vals[p2];
                bool dup = false;
                for (int j = 0; j < n; ++j) if (cols[j] == (uint16_t)col) { dup = true; break; }
                if (!dup) cols[n++] = (uint16_t)col;
            }
        cnt3[t] = n;
        for (int j = 0; j < n; ++j) list3[t * 6 + j] = cols[j];
        return;
    }
    t -= 364;
    if (t < 78) {                         // degree 2
        int r = t;
        int a = 0; while (r >= (NI - a)) { r -= (NI - a); ++a; }
        int b = a + r;
        int n = (a == b) ? 1 : 2;
        cnt2[t] = n;
        list2[t * 2 + 0] = (uint16_t)(a * 12 + b);
        if (n == 2) list2[t * 2 + 1] = (uint16_t)(b * 12 + a);
    }
}

// ---------- gather-fold: Wt[t][o] = sum of orbit elements, plain stores ----------
// Grid: 1024 blocks = (o in [0,512)) x (t-half in [0,2)); 256 threads.
__global__ __launch_bounds__(256) void pinet_fold(
    const float* __restrict__ w0, const float* __restrict__ w1,
    const float* __restrict__ w2, const float* __restrict__ w3,
    const float* __restrict__ w4,
    const uint32_t* __restrict__ cnt2, const uint16_t* __restrict__ list2,
    const uint32_t* __restrict__ cnt3, const uint16_t* __restrict__ list3,
    const uint32_t* __restrict__ cnt4, const uint16_t* __restrict__ list4,
    float* __restrict__ Wt) {
    const int o = blockIdx.x >> 1;
    const int half = blockIdx.x & 1;
    const float* r2 = w2 + o * 144;
    const float* r3 = w3 + o * 1728;
    const float* r4 = w4 + o * 20736;
    const int t_end = half * 912 + 912;
    for (int t = half * 912 + threadIdx.x; t < t_end; t += 256) {
        float s = 0.0f;
        if (t == 0) {
            s = w0[o];
        } else if (t < B2) {
            s = w1[o * 12 + (t - 1)];
        } else if (t < B3) {
            int q = t - B2; int n = cnt2[q];
            for (int i = 0; i < n; ++i) s += r2[list2[q * 2 + i]];
        } else if (t < B4) {
            int q = t - B3; int n = cnt3[q];
            for (int i = 0; i < n; ++i) s += r3[list3[q * 6 + i]];
        } else if (t < T_TOTAL) {
            int q = t - B4; int n = cnt4[q];
            for (int i = 0; i < n; ++i) s += r4[list4[q * 24 + i]];
        }
        Wt[t * NO + o] = s;   // t >= 1820 padding rows get 0
    }
}

// ---------- main GEMM: out[b,o] = sum_t Wt[t][o] * M[t][b] ----------
#define BB 128
#define OO 64
#define KT 32
#define NKT (TPAD / KT)   // 57

__global__ __launch_bounds__(256) void pinet_gemm(
    const float* __restrict__ x,        // [8192, 12]
    const float* __restrict__ Wt,       // [TPAD][512]
    const uint32_t* __restrict__ mono,  // [TPAD]
    float* __restrict__ out) {          // [8192, 512]
    __shared__ float xsh[BB][13];
    __shared__ float Wsh[KT][OO];
    __shared__ float Msh[KT][BB];

    const int tid = threadIdx.x;
    const int bx = blockIdx.x & 63;
    const int by = blockIdx.x >> 6;
    const int b0 = bx * BB, o0 = by * OO;

    for (int idx = tid; idx < BB * 12; idx += 256) {
        int b = idx / 12, j = idx % 12;
        xsh[b][j] = x[(b0 + b) * 12 + j];
    }
    if (tid < BB) xsh[tid][12] = 1.0f;

    float acc[8][4];
#pragma unroll
    for (int i = 0; i < 8; ++i)
#pragma unroll
        for (int j = 0; j < 4; ++j) acc[i][j] = 0.0f;

    const int to = tid & 7;
    const int tb = tid >> 3;

    for (int kt = 0; kt < NKT; ++kt) {
        __syncthreads();
#pragma unroll
        for (int r = 0; r < 8; ++r) {
            int idx = r * 256 + tid;
            int k = idx >> 6, o = idx & 63;
            Wsh[k][o] = Wt[(kt * KT + k) * NO + o0 + o];
        }
#pragma unroll
        for (int r = 0; r < 16; ++r) {
            int idx = r * 256 + tid;
            int k = idx >> 7, b = idx & 127;
            uint32_t u = mono[kt * KT + k];
            float v = xsh[b][u & 15] * xsh[b][(u >> 8) & 15] *
                      xsh[b][(u >> 16) & 15] * xsh[b][(u >> 24) & 15];
            Msh[k][b] = v;
        }
        __syncthreads();
#pragma unroll
        for (int k = 0; k < KT; ++k) {
            float4 wa = *(const float4*)&Wsh[k][to * 8];
            float4 wb = *(const float4*)&Wsh[k][to * 8 + 4];
            float4 mv = *(const float4*)&Msh[k][tb * 4];
            float wv[8] = {wa.x, wa.y, wa.z, wa.w, wb.x, wb.y, wb.z, wb.w};
            float mm[4] = {mv.x, mv.y, mv.z, mv.w};
#pragma unroll
            for (int i = 0; i < 8; ++i)
#pragma unroll
                for (int j = 0; j < 4; ++j)
                    acc[i][j] = fmaf(wv[i], mm[j], acc[i][j]);
        }
    }

#pragma unroll
    for (int j = 0; j < 4; ++j) {
        int b = b0 + tb * 4 + j;
        float4 v0 = {acc[0][j], acc[1][j], acc[2][j], acc[3][j]};
        float4 v1 = {acc[4][j], acc[5][j], acc[6][j], acc[7][j]};
        *(float4*)&out[b * NO + o0 + to * 8] = v0;
        *(float4*)&out[b * NO + o0 + to * 8 + 4] = v1;
    }
}

extern "C" void kernel_launch(void* const* d_in, const int* in_sizes, int n_in,
                              void* d_out, int out_size, void* d_ws, size_t ws_size,
                              hipStream_t stream) {
    const float* x  = (const float*)d_in[0];
    const float* w0 = (const float*)d_in[1];
    const float* w1 = (const float*)d_in[2];
    const float* w2 = (const float*)d_in[3];
    const float* w3 = (const float*)d_in[4];
    const float* w4 = (const float*)d_in[5];
    float* out = (float*)d_out;

    uint8_t* ws = (uint8_t*)d_ws;
    uint32_t* mono = (uint32_t*)ws;                       // 7296 B
    float*    Wt   = (float*)(ws + 8192);                 // [1824][512] = 3,735,552 B
    uint8_t*  tb   = ws + 8192 + 3735552;                 // table block
    uint32_t* cnt2 = (uint32_t*)(tb);                     // 312 B
    uint16_t* list2 = (uint16_t*)(tb + 512);              // 312 B
    uint32_t* cnt3 = (uint32_t*)(tb + 1024);              // 1456 B
    uint16_t* list3 = (uint16_t*)(tb + 2560);             // 4368 B
    uint32_t* cnt4 = (uint32_t*)(tb + 7168);              // 5460 B
    uint16_t* list4 = (uint16_t*)(tb + 12800);            // 65520 B -> end ~3.82 MB

    hipMemsetAsync(mono, 0x0C, TPAD * sizeof(uint32_t), stream);

    pinet_mono<<<(22620 + 255) / 256, 256, 0, stream>>>(mono);
    pinet_tables<<<8, 256, 0, stream>>>(cnt2, list2, cnt3, list3, cnt4, list4);
    pinet_fold<<<1024, 256, 0, stream>>>(w0, w1, w2, w3, w4,
                                         cnt2, list2, cnt3, list3, cnt4, list4, Wt);
    pinet_gemm<<<(NB / BB) * (NO / OO), 256, 0, stream>>>(x, Wt, mono, out);
}

// Round 3
// 156.653 us; speedup vs baseline: 5.8216x; 2.4793x over previous
//
#include <hip/hip_runtime.h>
#include <hip/hip_bf16.h>
#include <cstdint>

// PiNet: B=8192, I=12, O=512, DEG=4.
// Symmetry-folded to T = 1820 monomials; GEMM done as split-bf16 MFMA:
// a*b ~= a_hi*b_hi + a_lo*b_hi + a_hi*b_lo   (error ~2^-17 relative)

#define NB 8192
#define NI 12
#define NO 512
#define T_TOTAL 1820
#define TPAD 1824
#define B2 13
#define B3 91
#define B4 455

typedef __attribute__((ext_vector_type(8))) short bf16x8;
typedef __attribute__((ext_vector_type(4))) float f32x4;

__device__ __forceinline__ int H2f(int n) { return n * (n + 1) / 2; }
__device__ __forceinline__ int H3f(int n) { return n * (n + 1) * (n + 2) / 6; }
__device__ __forceinline__ int rank2(int a, int b) {
    int r = 0;
    for (int j = 0; j < a; ++j) r += NI - j;
    return r + (b - a);
}

__device__ __forceinline__ ushort bfhi(float f) {
    __hip_bfloat16 h = __float2bfloat16(f);
    return *reinterpret_cast<ushort*>(&h);
}

// ---------- tables: orbit lists (padded, 0xFFFF mask) + monomial pair table ----------
// mp[t] = off1 | (off2<<16): per-b monomial = msm[off1]*msm[off2], where msm
// is the 91-entry table {1, x0..x11, deg2 products}.
__global__ __launch_bounds__(256) void pinet_tables(
    uint16_t* __restrict__ list2, uint16_t* __restrict__ list3,
    uint16_t* __restrict__ list4, uint32_t* __restrict__ mp) {
    int id = blockIdx.x * 256 + threadIdx.x;
    if (id < 1365) {                      // degree 4
        int q = id, r = q;
        int a = 0; while (r >= H3f(NI - a)) { r -= H3f(NI - a); ++a; }
        int b = a; while (r >= H2f(NI - b)) { r -= H2f(NI - b); ++b; }
        int c = b; while (r >= (NI - c)) { r -= (NI - c); ++c; }
        int d = c + r;
        int vals[4] = {a, b, c, d};
        uint16_t cols[24]; int n = 0;
        for (int p0 = 0; p0 < 4; ++p0)
            for (int p1 = 0; p1 < 4; ++p1) {
                if (p1 == p0) continue;
                for (int p2 = 0; p2 < 4; ++p2) {
                    if (p2 == p0 || p2 == p1) continue;
                    int p3 = 6 - p0 - p1 - p2;
                    int col = vals[p0] * 1728 + vals[p1] * 144 + vals[p2] * 12 + vals[p3];
                    bool dup = false;
                    for (int j = 0; j < n; ++j) if (cols[j] == (uint16_t)col) { dup = true; break; }
                    if (!dup) cols[n++] = (uint16_t)col;
                }
            }
        for (int j = 0; j < 24; ++j) list4[q * 24 + j] = (j < n) ? cols[j] : 0xFFFFu;
        mp[B4 + q] = (uint32_t)(13 + rank2(a, b)) | ((uint32_t)(13 + rank2(c, d)) << 16);
        return;
    }
    id -= 1365;
    if (id < 364) {                       // degree 3
        int q = id, r = q;
        int a = 0; while (r >= H2f(NI - a)) { r -= H2f(NI - a); ++a; }
        int b = a; while (r >= (NI - b)) { r -= (NI - b); ++b; }
        int c = b + r;
        int vals[3] = {a, b, c};
        uint16_t cols[6]; int n = 0;
        for (int p0 = 0; p0 < 3; ++p0)
            for (int p1 = 0; p1 < 3; ++p1) {
                if (p1 == p0) continue;
                int p2 = 3 - p0 - p1;
                int col = vals[p0] * 144 + vals[p1] * 12 + vals[p2];
                bool dup = false;
                for (int j = 0; j < n; ++j) if (cols[j] == (uint16_t)col) { dup = true; break; }
                if (!dup) cols[n++] = (uint16_t)col;
            }
        for (int j = 0; j < 8; ++j) list3[q * 8 + j] = (j < n) ? cols[j] : 0xFFFFu;
        mp[B3 + q] = (uint32_t)(13 + rank2(a, b)) | ((uint32_t)(1 + c) << 16);
        return;
    }
    id -= 364;
    if (id < 78) {                        // degree 2
        int q = id, r = q;
        int a = 0; while (r >= (NI - a)) { r -= (NI - a); ++a; }
        int b = a + r;
        list2[q * 2 + 0] = (uint16_t)(a * 12 + b);
        list2[q * 2 + 1] = (a == b) ? 0xFFFFu : (uint16_t)(b * 12 + a);
        mp[B2 + q] = (uint32_t)(1 + a) | ((uint32_t)(1 + b) << 16);
        return;
    }
    id -= 78;
    if (id < 13) {                        // t in [0,13)
        mp[id] = (id == 0) ? 0u : (uint32_t)id;   // off2=0 -> *1
        return;
    }
    id -= 13;
    if (id < 4) mp[1820 + id] = 0u;       // padding rows: monomial = 1 (weight 0)
}

// ---------- gather-fold into pre-split bf16 hi/lo, MFMA pack-of-8 layout ----------
// Wtk[pack p][o][i] with t = p*8+i; element offset ((t>>3)*512 + o)*8 + (t&7).
__global__ __launch_bounds__(256) void pinet_fold(
    const float* __restrict__ w0, const float* __restrict__ w1,
    const float* __restrict__ w2, const float* __restrict__ w3,
    const float* __restrict__ w4,
    const uint16_t* __restrict__ list2, const uint16_t* __restrict__ list3,
    const uint16_t* __restrict__ list4,
    ushort* __restrict__ Whi, ushort* __restrict__ Wlo) {
    const int o = blockIdx.x >> 1;
    const int half = blockIdx.x & 1;
    const float* r2 = w2 + o * 144;
    const float* r3 = w3 + o * 1728;
    const float* r4 = w4 + o * 20736;
    const int t_end = half * 912 + 912;
    for (int t = half * 912 + (int)threadIdx.x; t < t_end; t += 256) {
        float s = 0.0f;
        if (t == 0) {
            s = w0[o];
        } else if (t < B2) {
            s = w1[o * 12 + (t - 1)];
        } else if (t < B3) {
            int q = t - B2;
            uint32_t wv = *(const uint32_t*)&list2[q * 2];
            uint32_t i0 = wv & 0xFFFFu, i1 = wv >> 16;
            float v0 = r2[min(i0, 143u)], v1 = r2[min(i1, 143u)];
            s = v0 + (i1 != 0xFFFFu ? v1 : 0.0f);
        } else if (t < B4) {
            int q = t - B3;
            uint4 rw = *(const uint4*)&list3[q * 8];
            uint32_t ws_[4] = {rw.x, rw.y, rw.z, rw.w};
#pragma unroll
            for (int j = 0; j < 4; ++j) {
                uint32_t i0 = ws_[j] & 0xFFFFu, i1 = ws_[j] >> 16;
                float v0 = r3[min(i0, 1727u)], v1 = r3[min(i1, 1727u)];
                s += (i0 != 0xFFFFu ? v0 : 0.0f) + (i1 != 0xFFFFu ? v1 : 0.0f);
            }
        } else if (t < T_TOTAL) {
            int q = t - B4;
            const uint16_t* row = list4 + q * 24;
            uint4 ra = *(const uint4*)(row);
            uint4 rb = *(const uint4*)(row + 8);
            uint4 rc = *(const uint4*)(row + 16);
            uint32_t ws_[12] = {ra.x, ra.y, ra.z, ra.w, rb.x, rb.y, rb.z, rb.w,
                                rc.x, rc.y, rc.z, rc.w};
#pragma unroll
            for (int j = 0; j < 12; ++j) {
                uint32_t i0 = ws_[j] & 0xFFFFu, i1 = ws_[j] >> 16;
                float v0 = r4[min(i0, 20735u)], v1 = r4[min(i1, 20735u)];
                s += (i0 != 0xFFFFu ? v0 : 0.0f) + (i1 != 0xFFFFu ? v1 : 0.0f);
            }
        }
        ushort h = bfhi(s);
        float hf = __uint_as_float((uint32_t)h << 16);
        ushort lo = bfhi(s - hf);
        int off = ((t >> 3) * NO + o) * 8 + (t & 7);
        Whi[off] = h;
        Wlo[off] = lo;
    }
}

// ---------- MFMA GEMM: out[b,o] = sum_t M[t][b] * Wt[t][o] ----------
// Block: 64 b x 256 o, 512 threads (8 waves), wave tile 64b x 32o.
// A (monomials) generated on the fly into double-buffered swizzled LDS;
// B (Wtk) loaded direct from global (L2-hot), prefetched one k-step ahead.
__global__ __launch_bounds__(512, 2) void pinet_gemm(
    const float* __restrict__ x, const ushort* __restrict__ Whi,
    const ushort* __restrict__ Wlo, const uint32_t* __restrict__ mp,
    float* __restrict__ out) {
    __shared__ float msm[64][93];           // per-b: {1, x0..x11, 78 deg2}, pad 93
    __shared__ ushort Ash[2][64][8][8];     // [buf][b][slot][8 bf16], slot swizzled

    const int tid = threadIdx.x;
    const int blkB = blockIdx.x >> 1;
    const int blkO = blockIdx.x & 1;
    const int b0 = blkB * 64;

    // build msm
    for (int idx = tid; idx < 64 * 13; idx += 512) {
        int b = idx / 13, j = idx % 13;
        msm[b][j] = (j == 0) ? 1.0f : x[(b0 + b) * 12 + (j - 1)];
    }
    __syncthreads();
    for (int idx = tid; idx < 64 * 78; idx += 512) {
        int b = idx / 78, q = idx % 78;
        uint32_t m2 = mp[B2 + q];
        msm[b][13 + q] = msm[b][m2 & 0xFFFFu] * msm[b][m2 >> 16];
    }

    const int l = tid & 63, w = tid >> 6;
    const int lm = l & 15, lg = l >> 4;
    const int o_w = blkO * 256 + w * 32;
    const int bgen = tid & 63;
    const int task = tid >> 6, gG = task >> 1, hG = task & 1;
    const int sHi = (2 * gG + 0) ^ (bgen & 7);
    const int sLo = (2 * gG + 1) ^ (bgen & 7);

    f32x4 acc[4][2] = {};
    bf16x8 bh0[2], bl0[2], bh1[2], bl1[2];

    auto genRound = [&](int kt, int buf) {
        int t0 = kt * 32 + gG * 8 + hG * 4;
        uint4 mq = *(const uint4*)&mp[t0];
        const float* row = msm[bgen];
        float p0 = row[mq.x & 0xFFFFu] * row[mq.x >> 16];
        float p1 = row[mq.y & 0xFFFFu] * row[mq.y >> 16];
        float p2 = row[mq.z & 0xFFFFu] * row[mq.z >> 16];
        float p3 = row[mq.w & 0xFFFFu] * row[mq.w >> 16];
        ushort h0 = bfhi(p0), h1 = bfhi(p1), h2 = bfhi(p2), h3 = bfhi(p3);
        float q0 = p0 - __uint_as_float((uint32_t)h0 << 16);
        float q1 = p1 - __uint_as_float((uint32_t)h1 << 16);
        float q2 = p2 - __uint_as_float((uint32_t)h2 << 16);
        float q3 = p3 - __uint_as_float((uint32_t)h3 << 16);
        ushort4 hi4 = {h0, h1, h2, h3};
        ushort4 lo4 = {bfhi(q0), bfhi(q1), bfhi(q2), bfhi(q3)};
        *(ushort4*)&Ash[buf][bgen][sHi][hG * 4] = hi4;
        *(ushort4*)&Ash[buf][bgen][sLo][hG * 4] = lo4;
    };
    auto loadB = [&](int kt, bf16x8 (&bh)[2], bf16x8 (&bl)[2]) {
        int p = kt * 4 + lg;
        int base = (p * NO + o_w + lm) * 8;
#pragma unroll
        for (int os = 0; os < 2; ++os) {
            bh[os] = *(const bf16x8*)(Whi + base + os * 128);
            bl[os] = *(const bf16x8*)(Wlo + base + os * 128);
        }
    };
    auto mfmaRound = [&](int cur, bf16x8 (&bh)[2], bf16x8 (&bl)[2]) {
        bf16x8 ah[4], al[4];
#pragma unroll
        for (int bs = 0; bs < 4; ++bs) {
            int br = bs * 16 + lm;
            ah[bs] = *(const bf16x8*)&Ash[cur][br][(2 * lg + 0) ^ (br & 7)][0];
            al[bs] = *(const bf16x8*)&Ash[cur][br][(2 * lg + 1) ^ (br & 7)][0];
        }
#pragma unroll
        for (int bs = 0; bs < 4; ++bs)
#pragma unroll
            for (int os = 0; os < 2; ++os) {
                acc[bs][os] = __builtin_amdgcn_mfma_f32_16x16x32_bf16(
                    ah[bs], bh[os], acc[bs][os], 0, 0, 0);
                acc[bs][os] = __builtin_amdgcn_mfma_f32_16x16x32_bf16(
                    al[bs], bh[os], acc[bs][os], 0, 0, 0);
                acc[bs][os] = __builtin_amdgcn_mfma_f32_16x16x32_bf16(
                    ah[bs], bl[os], acc[bs][os], 0, 0, 0);
            }
    };

    __syncthreads();          // msm ready
    genRound(0, 0);
    loadB(0, bh0, bl0);
    __syncthreads();          // Ash[0] ready

    for (int kt2 = 0; kt2 < 56; kt2 += 2) {
        // even step: consume set0/buf0, prefetch set1/buf1
        loadB(kt2 + 1, bh1, bl1);
        genRound(kt2 + 1, 1);
        mfmaRound(0, bh0, bl0);
        __syncthreads();
        // odd step: consume set1/buf1, prefetch set0/buf0
        if (kt2 + 2 < 57) {
            loadB(kt2 + 2, bh0, bl0);
            genRound(kt2 + 2, 0);
        }
        mfmaRound(1, bh1, bl1);
        __syncthreads();
    }
    mfmaRound(0, bh0, bl0);   // kt = 56

#pragma unroll
    for (int bs = 0; bs < 4; ++bs)
#pragma unroll
        for (int os = 0; os < 2; ++os) {
            int ob = o_w + os * 16 + lm;
#pragma unroll
            for (int r = 0; r < 4; ++r) {
                int bb = b0 + bs * 16 + lg * 4 + r;
                out[bb * NO + ob] = acc[bs][os][r];
            }
        }
}

extern "C" void kernel_launch(void* const* d_in, const int* in_sizes, int n_in,
                              void* d_out, int out_size, void* d_ws, size_t ws_size,
                              hipStream_t stream) {
    const float* x  = (const float*)d_in[0];
    const float* w0 = (const float*)d_in[1];
    const float* w1 = (const float*)d_in[2];
    const float* w2 = (const float*)d_in[3];
    const float* w3 = (const float*)d_in[4];
    const float* w4 = (const float*)d_in[5];
    float* out = (float*)d_out;

    uint8_t* ws = (uint8_t*)d_ws;
    uint32_t* mp   = (uint32_t*)ws;                       // 7296 B (pad 8192)
    ushort*   Whi  = (ushort*)(ws + 8192);                // 228*512*8*2 = 1,867,776 B
    ushort*   Wlo  = (ushort*)(ws + 8192 + 1867776);      // same
    uint8_t*  tb   = ws + 8192 + 2 * 1867776;             // = 3,743,744
    uint16_t* list2 = (uint16_t*)(tb);                    // 312 B (pad 320)
    uint16_t* list3 = (uint16_t*)(tb + 320);              // 5824 B
    uint16_t* list4 = (uint16_t*)(tb + 320 + 5824);       // 65520 B -> ~3.82 MB total

    pinet_tables<<<8, 256, 0, stream>>>(list2, list3, list4, mp);
    pinet_fold<<<1024, 256, 0, stream>>>(w0, w1, w2, w3, w4,
                                         list2, list3, list4, Whi, Wlo);
    pinet_gemm<<<256, 512, 0, stream>>>(x, Whi, Wlo, mp, out);
}

// Round 4
// 113.012 us; speedup vs baseline: 8.0697x; 1.3862x over previous
//
#include <hip/hip_runtime.h>
#include <hip/hip_bf16.h>
#include <cstdint>

// PiNet: B=8192, I=12, O=512, DEG=4.
// Symmetry-folded to T = 1820 monomials; GEMM as split-bf16 MFMA:
// a*b ~= a_hi*b_hi + a_lo*b_hi + a_hi*b_lo   (error ~2^-17 relative)
// R3: orbit tables eliminated -- fold uses multinomial identity
// (sum over distinct cols = sum over all perms / prod(multiplicity!)),
// branchless constant perm tables, uniform control flow.

#define NB 8192
#define NI 12
#define NO 512
#define T_TOTAL 1820
#define TPAD 1824
#define B2 13
#define B3 91
#define B4 455

typedef __attribute__((ext_vector_type(8))) short bf16x8;
typedef __attribute__((ext_vector_type(4))) float f32x4;

__device__ __forceinline__ int H2f(int n) { return n * (n + 1) / 2; }
__device__ __forceinline__ int H3f(int n) { return n * (n + 1) * (n + 2) / 6; }
__device__ __forceinline__ int rank2(int a, int b) {
    int r = 0;
    for (int j = 0; j < a; ++j) r += NI - j;
    return r + (b - a);
}

__device__ __forceinline__ ushort bfhi(float f) {
    __hip_bfloat16 h = __float2bfloat16(f);
    return *reinterpret_cast<ushort*>(&h);
}

// all permutations of {0,1,2,3} and {0,1,2}
__constant__ uint8_t P4[24][4] = {
    {0,1,2,3},{0,1,3,2},{0,2,1,3},{0,2,3,1},{0,3,1,2},{0,3,2,1},
    {1,0,2,3},{1,0,3,2},{1,2,0,3},{1,2,3,0},{1,3,0,2},{1,3,2,0},
    {2,0,1,3},{2,0,3,1},{2,1,0,3},{2,1,3,0},{2,3,0,1},{2,3,1,0},
    {3,0,1,2},{3,0,2,1},{3,1,0,2},{3,1,2,0},{3,2,0,1},{3,2,1,0}};
__constant__ uint8_t P3[6][3] = {{0,1,2},{0,2,1},{1,0,2},{1,2,0},{2,0,1},{2,1,0}};

// ---------- mp: monomial pair table, mp[t] = off1 | (off2<<16) ----------
// per-b monomial value = msm[off1]*msm[off2]; msm = {1, x0..x11, 78 deg2 prods}.
__global__ __launch_bounds__(64) void pinet_mp(uint32_t* __restrict__ mp) {
    int t = blockIdx.x * 64 + threadIdx.x;
    if (t >= TPAD) return;
    uint32_t v = 0;
    if (t == 0) {
        v = 0;
    } else if (t < B2) {
        v = (uint32_t)t;                       // x_{t-1} * 1
    } else if (t < B3) {
        int r = t - B2;
        int a = 0; while (r >= (NI - a)) { r -= (NI - a); ++a; }
        int b = a + r;
        v = (uint32_t)(1 + a) | ((uint32_t)(1 + b) << 16);
    } else if (t < B4) {
        int r = t - B3;
        int a = 0; while (r >= H2f(NI - a)) { r -= H2f(NI - a); ++a; }
        int b = a; while (r >= (NI - b)) { r -= (NI - b); ++b; }
        int c = b + r;
        v = (uint32_t)(13 + rank2(a, b)) | ((uint32_t)(1 + c) << 16);
    } else if (t < T_TOTAL) {
        int r = t - B4;
        int a = 0; while (r >= H3f(NI - a)) { r -= H3f(NI - a); ++a; }
        int b = a; while (r >= H2f(NI - b)) { r -= H2f(NI - b); ++b; }
        int c = b; while (r >= (NI - c)) { r -= (NI - c); ++c; }
        int d = c + r;
        v = (uint32_t)(13 + rank2(a, b)) | ((uint32_t)(13 + rank2(c, d)) << 16);
    }
    mp[t] = v;                                 // t in [1820,1824): 1*1 (weight 0)
}

// ---------- gather-fold into pre-split bf16 hi/lo, MFMA pack-of-8 layout ----------
// Wt[t][o] = (sum over ALL permutations of the tuple) / prod(mult!).
// element offset ((t>>3)*512 + o)*8 + (t&7).
__global__ __launch_bounds__(256) void pinet_fold(
    const float* __restrict__ w0, const float* __restrict__ w1,
    const float* __restrict__ w2, const float* __restrict__ w3,
    const float* __restrict__ w4,
    ushort* __restrict__ Whi, ushort* __restrict__ Wlo) {
    const int o = blockIdx.x >> 1;
    const int half = blockIdx.x & 1;
    const float* r2 = w2 + o * 144;
    const float* r3 = w3 + o * 1728;
    const float* r4 = w4 + o * 20736;
    const int t_end = half * 912 + 912;
    for (int t = half * 912 + (int)threadIdx.x; t < t_end; t += 256) {
        float s = 0.0f;
        if (t == 0) {
            s = w0[o];
        } else if (t < B2) {
            s = w1[o * 12 + (t - 1)];
        } else if (t < B3) {
            int r = t - B2;
            int a = 0; while (r >= (NI - a)) { r -= (NI - a); ++a; }
            int b = a + r;
            float sum = r2[a * 12 + b] + r2[b * 12 + a];
            s = (a == b) ? sum * 0.5f : sum;
        } else if (t < B4) {
            int r = t - B3;
            int a = 0; while (r >= H2f(NI - a)) { r -= H2f(NI - a); ++a; }
            int b = a; while (r >= (NI - b)) { r -= (NI - b); ++b; }
            int c = b + r;
            int vv[3] = {a, b, c};
            int k = 1, run = 1;
#pragma unroll
            for (int i = 1; i < 3; ++i) {
                if (vv[i] == vv[i - 1]) { ++run; k *= run; } else run = 1;
            }
            float sum = 0.0f;
#pragma unroll
            for (int p = 0; p < 6; ++p)
                sum += r3[vv[P3[p][0]] * 144 + vv[P3[p][1]] * 12 + vv[P3[p][2]]];
            s = sum * (1.0f / (float)k);
        } else if (t < T_TOTAL) {
            int r = t - B4;
            int a = 0; while (r >= H3f(NI - a)) { r -= H3f(NI - a); ++a; }
            int b = a; while (r >= H2f(NI - b)) { r -= H2f(NI - b); ++b; }
            int c = b; while (r >= (NI - c)) { r -= (NI - c); ++c; }
            int d = c + r;
            int vv[4] = {a, b, c, d};
            int k = 1, run = 1;
#pragma unroll
            for (int i = 1; i < 4; ++i) {
                if (vv[i] == vv[i - 1]) { ++run; k *= run; } else run = 1;
            }
            float sum = 0.0f;
#pragma unroll
            for (int p = 0; p < 24; ++p)
                sum += r4[vv[P4[p][0]] * 1728 + vv[P4[p][1]] * 144 +
                          vv[P4[p][2]] * 12 + vv[P4[p][3]]];
            s = sum * (1.0f / (float)k);
        }
        ushort h = bfhi(s);
        float hf = __uint_as_float((uint32_t)h << 16);
        ushort lo = bfhi(s - hf);
        int off = ((t >> 3) * NO + o) * 8 + (t & 7);
        Whi[off] = h;
        Wlo[off] = lo;
    }
}

// ---------- MFMA GEMM: out[b,o] = sum_t M[t][b] * Wt[t][o] ----------
// Block: 64 b x 256 o, 512 threads (8 waves), wave tile 64b x 32o.
// A (monomials) generated on the fly into double-buffered swizzled LDS;
// B (Wtk) loaded direct from global (L2-hot), prefetched one k-step ahead.
__global__ __launch_bounds__(512, 2) void pinet_gemm(
    const float* __restrict__ x, const ushort* __restrict__ Whi,
    const ushort* __restrict__ Wlo, const uint32_t* __restrict__ mp,
    float* __restrict__ out) {
    __shared__ float msm[64][93];           // per-b: {1, x0..x11, 78 deg2}, pad 93
    __shared__ ushort Ash[2][64][8][8];     // [buf][b][slot][8 bf16], slot swizzled

    const int tid = threadIdx.x;
    const int blkB = blockIdx.x >> 1;
    const int blkO = blockIdx.x & 1;
    const int b0 = blkB * 64;

    for (int idx = tid; idx < 64 * 13; idx += 512) {
        int b = idx / 13, j = idx % 13;
        msm[b][j] = (j == 0) ? 1.0f : x[(b0 + b) * 12 + (j - 1)];
    }
    __syncthreads();
    for (int idx = tid; idx < 64 * 78; idx += 512) {
        int b = idx / 78, q = idx % 78;
        uint32_t m2 = mp[B2 + q];
        msm[b][13 + q] = msm[b][m2 & 0xFFFFu] * msm[b][m2 >> 16];
    }

    const int l = tid & 63, w = tid >> 6;
    const int lm = l & 15, lg = l >> 4;
    const int o_w = blkO * 256 + w * 32;
    const int bgen = tid & 63;
    const int task = tid >> 6, gG = task >> 1, hG = task & 1;
    const int sHi = (2 * gG + 0) ^ (bgen & 7);
    const int sLo = (2 * gG + 1) ^ (bgen & 7);

    f32x4 acc[4][2] = {};
    bf16x8 bh0[2], bl0[2], bh1[2], bl1[2];

    auto genRound = [&](int kt, int buf) {
        int t0 = kt * 32 + gG * 8 + hG * 4;
        uint4 mq = *(const uint4*)&mp[t0];
        const float* row = msm[bgen];
        float p0 = row[mq.x & 0xFFFFu] * row[mq.x >> 16];
        float p1 = row[mq.y & 0xFFFFu] * row[mq.y >> 16];
        float p2 = row[mq.z & 0xFFFFu] * row[mq.z >> 16];
        float p3 = row[mq.w & 0xFFFFu] * row[mq.w >> 16];
        ushort h0 = bfhi(p0), h1 = bfhi(p1), h2 = bfhi(p2), h3 = bfhi(p3);
        float q0 = p0 - __uint_as_float((uint32_t)h0 << 16);
        float q1 = p1 - __uint_as_float((uint32_t)h1 << 16);
        float q2 = p2 - __uint_as_float((uint32_t)h2 << 16);
        float q3 = p3 - __uint_as_float((uint32_t)h3 << 16);
        ushort4 hi4 = {h0, h1, h2, h3};
        ushort4 lo4 = {bfhi(q0), bfhi(q1), bfhi(q2), bfhi(q3)};
        *(ushort4*)&Ash[buf][bgen][sHi][hG * 4] = hi4;
        *(ushort4*)&Ash[buf][bgen][sLo][hG * 4] = lo4;
    };
    auto loadB = [&](int kt, bf16x8 (&bh)[2], bf16x8 (&bl)[2]) {
        int p = kt * 4 + lg;
        int base = (p * NO + o_w + lm) * 8;
#pragma unroll
        for (int os = 0; os < 2; ++os) {
            bh[os] = *(const bf16x8*)(Whi + base + os * 128);
            bl[os] = *(const bf16x8*)(Wlo + base + os * 128);
        }
    };
    auto mfmaRound = [&](int cur, bf16x8 (&bh)[2], bf16x8 (&bl)[2]) {
        bf16x8 ah[4], al[4];
#pragma unroll
        for (int bs = 0; bs < 4; ++bs) {
            int br = bs * 16 + lm;
            ah[bs] = *(const bf16x8*)&Ash[cur][br][(2 * lg + 0) ^ (br & 7)][0];
            al[bs] = *(const bf16x8*)&Ash[cur][br][(2 * lg + 1) ^ (br & 7)][0];
        }
#pragma unroll
        for (int bs = 0; bs < 4; ++bs)
#pragma unroll
            for (int os = 0; os < 2; ++os) {
                acc[bs][os] = __builtin_amdgcn_mfma_f32_16x16x32_bf16(
                    ah[bs], bh[os], acc[bs][os], 0, 0, 0);
                acc[bs][os] = __builtin_amdgcn_mfma_f32_16x16x32_bf16(
                    al[bs], bh[os], acc[bs][os], 0, 0, 0);
                acc[bs][os] = __builtin_amdgcn_mfma_f32_16x16x32_bf16(
                    ah[bs], bl[os], acc[bs][os], 0, 0, 0);
            }
    };

    __syncthreads();          // msm ready
    genRound(0, 0);
    loadB(0, bh0, bl0);
    __syncthreads();          // Ash[0] ready

    for (int kt2 = 0; kt2 < 56; kt2 += 2) {
        loadB(kt2 + 1, bh1, bl1);
        genRound(kt2 + 1, 1);
        mfmaRound(0, bh0, bl0);
        __syncthreads();
        if (kt2 + 2 < 57) {
            loadB(kt2 + 2, bh0, bl0);
            genRound(kt2 + 2, 0);
        }
        mfmaRound(1, bh1, bl1);
        __syncthreads();
    }
    mfmaRound(0, bh0, bl0);   // kt = 56

#pragma unroll
    for (int bs = 0; bs < 4; ++bs)
#pragma unroll
        for (int os = 0; os < 2; ++os) {
            int ob = o_w + os * 16 + lm;
#pragma unroll
            for (int r = 0; r < 4; ++r) {
                int bb = b0 + bs * 16 + lg * 4 + r;
                out[bb * NO + ob] = acc[bs][os][r];
            }
        }
}

extern "C" void kernel_launch(void* const* d_in, const int* in_sizes, int n_in,
                              void* d_out, int out_size, void* d_ws, size_t ws_size,
                              hipStream_t stream) {
    const float* x  = (const float*)d_in[0];
    const float* w0 = (const float*)d_in[1];
    const float* w1 = (const float*)d_in[2];
    const float* w2 = (const float*)d_in[3];
    const float* w3 = (const float*)d_in[4];
    const float* w4 = (const float*)d_in[5];
    float* out = (float*)d_out;

    uint8_t* ws = (uint8_t*)d_ws;
    uint32_t* mp  = (uint32_t*)ws;                        // 7296 B (pad 8192)
    ushort*   Whi = (ushort*)(ws + 8192);                 // 228*512*8*2 = 1,867,776 B
    ushort*   Wlo = (ushort*)(ws + 8192 + 1867776);       // same

    pinet_mp<<<(TPAD + 63) / 64, 64, 0, stream>>>(mp);
    pinet_fold<<<1024, 256, 0, stream>>>(w0, w1, w2, w3, w4, Whi, Wlo);
    pinet_gemm<<<256, 512, 0, stream>>>(x, Whi, Wlo, mp, out);
}

// Round 5
// 100.781 us; speedup vs baseline: 9.0490x; 1.1214x over previous
//
#include <hip/hip_runtime.h>
#include <hip/hip_bf16.h>
#include <cstdint>

// PiNet: B=8192, I=12, O=512, DEG=4.
// Symmetry-folded to T = 1820 monomials (padded to 1856 = 29*64).
// R4: fp16 single-precision MFMA (error ~2^-11 rel, threshold has 5x headroom),
// KT=64, fold rewritten as coalesced sweep + LDS-accumulator scatter.

#define NB 8192
#define NI 12
#define NO 512
#define T_TOTAL 1820
#define TPAD 1856          // 29 * 64
#define NKT 29
#define B2 13
#define B3 91
#define B4 455

typedef __attribute__((ext_vector_type(8))) _Float16 f16x8;
typedef __attribute__((ext_vector_type(8))) unsigned short u16x8;
typedef __attribute__((ext_vector_type(4))) float f32x4;

__device__ __forceinline__ int H2f(int n) { return n * (n + 1) / 2; }
__device__ __forceinline__ int H3f(int n) { return n * (n + 1) * (n + 2) / 6; }
__device__ __forceinline__ int rank2(int a, int b) {
    int r = 0;
    for (int j = 0; j < a; ++j) r += NI - j;
    return r + (b - a);
}

// closed-form rank tables: S1[l]=sum_{j<l}(12-j); S2[k]=sum_{j<k}H2(12-j); C4[a]=sum_{j<a}H3(12-j)
__constant__ int S1t[13] = {0,12,23,33,42,50,57,63,68,72,75,77,78};
__constant__ int S2t[13] = {0,78,144,199,244,280,308,329,344,354,360,363,364};
__constant__ int C4t[13] = {0,364,650,870,1035,1155,1239,1295,1330,1350,1360,1364,1365};

__device__ __forceinline__ void cswap(int& a, int& b) {
    int lo = min(a, b), hi = max(a, b); a = lo; b = hi;
}

// ---------- mp: monomial pair table, mp[t] = off1 | (off2<<16) ----------
// per-b monomial value = msm[off1]*msm[off2]; msm = {1, x0..x11, 78 deg2 prods}.
__global__ __launch_bounds__(64) void pinet_mp(uint32_t* __restrict__ mp) {
    int t = blockIdx.x * 64 + threadIdx.x;
    if (t >= TPAD) return;
    uint32_t v = 0;
    if (t == 0) {
        v = 0;
    } else if (t < B2) {
        v = (uint32_t)t;
    } else if (t < B3) {
        int r = t - B2;
        int a = 0; while (r >= (NI - a)) { r -= (NI - a); ++a; }
        int b = a + r;
        v = (uint32_t)(1 + a) | ((uint32_t)(1 + b) << 16);
    } else if (t < B4) {
        int r = t - B3;
        int a = 0; while (r >= H2f(NI - a)) { r -= H2f(NI - a); ++a; }
        int b = a; while (r >= (NI - b)) { r -= (NI - b); ++b; }
        int c = b + r;
        v = (uint32_t)(13 + rank2(a, b)) | ((uint32_t)(1 + c) << 16);
    } else if (t < T_TOTAL) {
        int r = t - B4;
        int a = 0; while (r >= H3f(NI - a)) { r -= H3f(NI - a); ++a; }
        int b = a; while (r >= H2f(NI - b)) { r -= H2f(NI - b); ++b; }
        int c = b; while (r >= (NI - c)) { r -= (NI - c); ++c; }
        int d = c + r;
        v = (uint32_t)(13 + rank2(a, b)) | ((uint32_t)(13 + rank2(c, d)) << 16);
    }
    mp[t] = v;                                 // t in [1820,1856): monomial=1, weight 0
}

// ---------- fold: coalesced sweep + LDS accumulator scatter ----------
// One block per o. Wacc[t] = sum_{c: sorted(c)=t} w_d[o,c]  (exact, no division).
// Output Wh fp16, pack-of-8 layout: offset ((t>>3)*512 + o)*8 + (t&7).
__global__ __launch_bounds__(512) void pinet_fold(
    const float* __restrict__ w0, const float* __restrict__ w1,
    const float* __restrict__ w2, const float* __restrict__ w3,
    const float* __restrict__ w4, ushort* __restrict__ Wh) {
    __shared__ float Wacc[TPAD];
    const int tid = threadIdx.x;
    const int o = blockIdx.x;

    for (int t = tid; t < TPAD; t += 512) {
        float v = 0.0f;
        if (t == 0) v = w0[o];
        else if (t < B2) v = w1[o * 12 + (t - 1)];
        Wacc[t] = v;
    }
    __syncthreads();

    // degree 2: 144 elements
    if (tid < 144) {
        float v = w2[o * 144 + tid];
        int a = tid / 12, b = tid % 12;
        cswap(a, b);
        atomicAdd(&Wacc[B2 + S1t[a] + (b - a)], v);
    }
    // degree 3: 1728 = 432 float4
    {
        const float4* r3 = (const float4*)(w3 + o * 1728);
        for (int i = tid; i < 432; i += 512) {
            float4 v = r3[i];
            float vs[4] = {v.x, v.y, v.z, v.w};
            int c0 = i * 4;
#pragma unroll
            for (int j = 0; j < 4; ++j) {
                int c = c0 + j;
                int a = c / 144, b = (c / 12) % 12, d = c % 12;
                cswap(a, b); cswap(a, d); cswap(b, d);
                atomicAdd(&Wacc[B3 + S2t[a] + (S1t[b] - S1t[a]) + (d - b)], vs[j]);
            }
        }
    }
    // degree 4: 20736 = 5184 float4
    {
        const float4* r4 = (const float4*)(w4 + o * 20736);
        for (int i = tid; i < 5184; i += 512) {
            float4 v = r4[i];
            float vs[4] = {v.x, v.y, v.z, v.w};
            int c0 = i * 4;
#pragma unroll
            for (int j = 0; j < 4; ++j) {
                int c = c0 + j;
                int a = c / 1728, b = (c / 144) % 12, cc = (c / 12) % 12, d = c % 12;
                cswap(a, b); cswap(cc, d); cswap(a, cc); cswap(b, d); cswap(b, cc);
                atomicAdd(&Wacc[B4 + C4t[a] + (S2t[b] - S2t[a]) +
                                (S1t[cc] - S1t[b]) + (d - cc)], vs[j]);
            }
        }
    }
    __syncthreads();

    for (int t = tid; t < TPAD; t += 512) {
        _Float16 h = (_Float16)Wacc[t];
        Wh[((t >> 3) * NO + o) * 8 + (t & 7)] = __builtin_bit_cast(unsigned short, h);
    }
}

// ---------- MFMA GEMM: out[b,o] = sum_t M[t][b] * Wt[t][o], fp16 single ----------
// Block: 64 b x 256 o, 512 threads (8 waves), wave tile 64b x 32o, KT=64.
__global__ __launch_bounds__(512, 2) void pinet_gemm(
    const float* __restrict__ x, const ushort* __restrict__ Wh,
    const uint32_t* __restrict__ mp, float* __restrict__ out) {
    __shared__ float msm[64][93];           // per-b: {1, x0..x11, 78 deg2}, stride 93
    __shared__ ushort Ash[2][64][8][8];     // [buf][b][t-octet slot (swizzled)][8 fp16]

    const int tid = threadIdx.x;
    const int blkB = blockIdx.x >> 1;
    const int blkO = blockIdx.x & 1;
    const int b0 = blkB * 64;

    for (int idx = tid; idx < 64 * 13; idx += 512) {
        int b = idx / 13, j = idx % 13;
        msm[b][j] = (j == 0) ? 1.0f : x[(b0 + b) * 12 + (j - 1)];
    }
    __syncthreads();
    for (int idx = tid; idx < 64 * 78; idx += 512) {
        int b = idx / 78, q = idx % 78;
        uint32_t m2 = mp[B2 + q];
        msm[b][13 + q] = msm[b][m2 & 0xFFFFu] * msm[b][m2 >> 16];
    }

    const int l = tid & 63, w = tid >> 6;
    const int lm = l & 15, lg = l >> 4;
    const int o_w = blkO * 256 + w * 32;
    const int bgen = tid & 63;
    const int task = tid >> 6;              // t-octet within k-step (wave-uniform)
    const int sA = task ^ (bgen & 7);       // swizzled slot

    f32x4 acc[4][2] = {};
    f16x8 B0[2][2], B1[2][2];               // [os][chunk]

    auto gen = [&](int kt, int buf) {
        int t0 = kt * 64 + task * 8;
        uint4 ma = *(const uint4*)&mp[t0];
        uint4 mb = *(const uint4*)&mp[t0 + 4];
        const float* row = msm[bgen];
        uint32_t mq[8] = {ma.x, ma.y, ma.z, ma.w, mb.x, mb.y, mb.z, mb.w};
        u16x8 v;
#pragma unroll
        for (int j = 0; j < 8; ++j) {
            float p = row[mq[j] & 0xFFFFu] * row[mq[j] >> 16];
            _Float16 h = (_Float16)p;
            v[j] = __builtin_bit_cast(unsigned short, h);
        }
        *(u16x8*)&Ash[buf][bgen][sA][0] = v;
    };
    auto loadB = [&](int kt, f16x8 (&B)[2][2]) {
#pragma unroll
        for (int os = 0; os < 2; ++os)
#pragma unroll
            for (int c = 0; c < 2; ++c) {
                int pk = kt * 8 + c * 4 + lg;
                B[os][c] = *(const f16x8*)(Wh + (pk * NO + o_w + os * 16 + lm) * 8);
            }
    };
    auto mfmaR = [&](int cur, f16x8 (&B)[2][2]) {
#pragma unroll
        for (int c = 0; c < 2; ++c) {
            f16x8 a[4];
#pragma unroll
            for (int bs = 0; bs < 4; ++bs) {
                int br = bs * 16 + lm;
                a[bs] = *(const f16x8*)&Ash[cur][br][(c * 4 + lg) ^ (br & 7)][0];
            }
#pragma unroll
            for (int bs = 0; bs < 4; ++bs)
#pragma unroll
                for (int os = 0; os < 2; ++os)
                    acc[bs][os] = __builtin_amdgcn_mfma_f32_16x16x32_f16(
                        a[bs], B[os][c], acc[bs][os], 0, 0, 0);
        }
    };

    __syncthreads();          // msm ready
    gen(0, 0);
    loadB(0, B0);
    __syncthreads();          // Ash[0] ready

    for (int kt2 = 0; kt2 < 28; kt2 += 2) {
        loadB(kt2 + 1, B1);
        gen(kt2 + 1, 1);
        mfmaR(0, B0);
        __syncthreads();
        loadB(kt2 + 2, B0);   // kt2+2 <= 28 < NKT always
        gen(kt2 + 2, 0);
        mfmaR(1, B1);
        __syncthreads();
    }
    mfmaR(0, B0);             // kt = 28

#pragma unroll
    for (int bs = 0; bs < 4; ++bs)
#pragma unroll
        for (int os = 0; os < 2; ++os) {
            int ob = o_w + os * 16 + lm;
#pragma unroll
            for (int r = 0; r < 4; ++r) {
                int bb = b0 + bs * 16 + lg * 4 + r;
                out[bb * NO + ob] = acc[bs][os][r];
            }
        }
}

extern "C" void kernel_launch(void* const* d_in, const int* in_sizes, int n_in,
                              void* d_out, int out_size, void* d_ws, size_t ws_size,
                              hipStream_t stream) {
    const float* x  = (const float*)d_in[0];
    const float* w0 = (const float*)d_in[1];
    const float* w1 = (const float*)d_in[2];
    const float* w2 = (const float*)d_in[3];
    const float* w3 = (const float*)d_in[4];
    const float* w4 = (const float*)d_in[5];
    float* out = (float*)d_out;

    uint8_t* ws = (uint8_t*)d_ws;
    uint32_t* mp = (uint32_t*)ws;                  // 1856*4 = 7424 B (pad 8192)
    ushort*   Wh = (ushort*)(ws + 8192);           // 232*512*8*2 = 1,900,544 B

    pinet_mp<<<TPAD / 64, 64, 0, stream>>>(mp);
    pinet_fold<<<NO, 512, 0, stream>>>(w0, w1, w2, w3, w4, Wh);
    pinet_gemm<<<(NB / 64) * 2, 512, 0, stream>>>(x, Wh, mp, out);
}

// Round 6
// 99.983 us; speedup vs baseline: 9.1213x; 1.0080x over previous
//
#include <hip/hip_runtime.h>
#include <hip/hip_bf16.h>
#include <cstdint>

// PiNet: B=8192, I=12, O=512, DEG=4.
// Symmetry-folded to T = 1820 monomials (padded to 1856 = 29*64).
// R5: fold driven by precomputed column->t maps (no per-element sort/rank),
// 1024-thread fold blocks (full occupancy); gemm to 16 waves/block.

#define NB 8192
#define NI 12
#define NO 512
#define T_TOTAL 1820
#define TPAD 1856          // 29 * 64
#define NKT 29
#define B2 13
#define B3 91
#define B4 455

typedef __attribute__((ext_vector_type(8))) _Float16 f16x8;
typedef __attribute__((ext_vector_type(4))) float f32x4;

__device__ __forceinline__ int H2f(int n) { return n * (n + 1) / 2; }
__device__ __forceinline__ int H3f(int n) { return n * (n + 1) * (n + 2) / 6; }
__device__ __forceinline__ int rank2(int a, int b) {
    int r = 0;
    for (int j = 0; j < a; ++j) r += NI - j;
    return r + (b - a);
}

// S1[l]=sum_{j<l}(12-j); S2[k]=sum_{j<k}H2(12-j); C4[a]=sum_{j<a}H3(12-j)
__constant__ int S1t[13] = {0,12,23,33,42,50,57,63,68,72,75,77,78};
__constant__ int S2t[13] = {0,78,144,199,244,280,308,329,344,354,360,363,364};
__constant__ int C4t[13] = {0,364,650,870,1035,1155,1239,1295,1330,1350,1360,1364,1365};

__device__ __forceinline__ void cswap(int& a, int& b) {
    int lo = min(a, b), hi = max(a, b); a = lo; b = hi;
}

// ---------- maps: mp (monomial pair table) + cmap2/3/4 (column -> t) ----------
__global__ __launch_bounds__(256) void pinet_maps(
    uint32_t* __restrict__ mp, ushort* __restrict__ cmap2,
    ushort* __restrict__ cmap3, ushort* __restrict__ cmap4) {
    int id = blockIdx.x * 256 + threadIdx.x;
    if (id < 20736) {
        int c = id;
        int a = c / 1728, b = (c / 144) % 12, cc = (c / 12) % 12, d = c % 12;
        cswap(a, b); cswap(cc, d); cswap(a, cc); cswap(b, d); cswap(b, cc);
        cmap4[id] = (ushort)(B4 + C4t[a] + (S2t[b] - S2t[a]) +
                             (S1t[cc] - S1t[b]) + (d - cc));
        return;
    }
    id -= 20736;
    if (id < 1728) {
        int c = id;
        int a = c / 144, b = (c / 12) % 12, d = c % 12;
        cswap(a, b); cswap(a, d); cswap(b, d);
        cmap3[id] = (ushort)(B3 + S2t[a] + (S1t[b] - S1t[a]) + (d - b));
        return;
    }
    id -= 1728;
    if (id < 144) {
        int a = id / 12, b = id % 12;
        cswap(a, b);
        cmap2[id] = (ushort)(B2 + S1t[a] + (b - a));
        return;
    }
    id -= 144;
    if (id < TPAD) {
        int t = id;
        uint32_t v = 0;
        if (t == 0) {
            v = 0;
        } else if (t < B2) {
            v = (uint32_t)t;
        } else if (t < B3) {
            int r = t - B2;
            int a = 0; while (r >= (NI - a)) { r -= (NI - a); ++a; }
            int b = a + r;
            v = (uint32_t)(1 + a) | ((uint32_t)(1 + b) << 16);
        } else if (t < B4) {
            int r = t - B3;
            int a = 0; while (r >= H2f(NI - a)) { r -= H2f(NI - a); ++a; }
            int b = a; while (r >= (NI - b)) { r -= (NI - b); ++b; }
            int c = b + r;
            v = (uint32_t)(13 + rank2(a, b)) | ((uint32_t)(1 + c) << 16);
        } else if (t < T_TOTAL) {
            int r = t - B4;
            int a = 0; while (r >= H3f(NI - a)) { r -= H3f(NI - a); ++a; }
            int b = a; while (r >= H2f(NI - b)) { r -= H2f(NI - b); ++b; }
            int c = b; while (r >= (NI - c)) { r -= (NI - c); ++c; }
            int d = c + r;
            v = (uint32_t)(13 + rank2(a, b)) | ((uint32_t)(13 + rank2(c, d)) << 16);
        }
        mp[t] = v;     // t in [1820,1856): monomial = 1, weight 0
    }
}

// ---------- fold: coalesced sweep + LDS accumulator scatter (map-driven) ----------
// One block (1024 threads) per o. Output Wh fp16, pack-of-8 layout.
__global__ __launch_bounds__(1024) void pinet_fold(
    const float* __restrict__ w0, const float* __restrict__ w1,
    const float* __restrict__ w2, const float* __restrict__ w3,
    const float* __restrict__ w4,
    const ushort* __restrict__ cmap2, const ushort* __restrict__ cmap3,
    const ushort* __restrict__ cmap4, ushort* __restrict__ Wh) {
    __shared__ float Wacc[TPAD];
    const int tid = threadIdx.x;
    const int o = blockIdx.x;

    for (int t = tid; t < TPAD; t += 1024) {
        float v = 0.0f;
        if (t == 0) v = w0[o];
        else if (t < B2) v = w1[o * 12 + (t - 1)];
        Wacc[t] = v;
    }
    __syncthreads();

    if (tid < 144) atomicAdd(&Wacc[cmap2[tid]], w2[o * 144 + tid]);
    {
        const float4* r3 = (const float4*)(w3 + o * 1728);
        const ushort4* m3 = (const ushort4*)cmap3;
        for (int i = tid; i < 432; i += 1024) {
            float4 v = r3[i]; ushort4 m = m3[i];
            atomicAdd(&Wacc[m.x], v.x); atomicAdd(&Wacc[m.y], v.y);
            atomicAdd(&Wacc[m.z], v.z); atomicAdd(&Wacc[m.w], v.w);
        }
    }
    {
        const float4* r4 = (const float4*)(w4 + o * 20736);
        const ushort4* m4 = (const ushort4*)cmap4;
        for (int i = tid; i < 5184; i += 1024) {
            float4 v = r4[i]; ushort4 m = m4[i];
            atomicAdd(&Wacc[m.x], v.x); atomicAdd(&Wacc[m.y], v.y);
            atomicAdd(&Wacc[m.z], v.z); atomicAdd(&Wacc[m.w], v.w);
        }
    }
    __syncthreads();

    for (int t = tid; t < TPAD; t += 1024) {
        _Float16 h = (_Float16)Wacc[t];
        Wh[((t >> 3) * NO + o) * 8 + (t & 7)] = __builtin_bit_cast(unsigned short, h);
    }
}

// ---------- MFMA GEMM: out[b,o] = sum_t M[t][b] * Wt[t][o], fp16 ----------
// Block: 64 b x 256 o, 1024 threads (16 waves), wave tile 32b x 32o, KT=64.
__global__ __launch_bounds__(1024, 4) void pinet_gemm(
    const float* __restrict__ x, const ushort* __restrict__ Wh,
    const uint32_t* __restrict__ mp, float* __restrict__ out) {
    __shared__ float msm[64][93];           // per-b: {1, x0..x11, 78 deg2}
    __shared__ ushort Ash[2][64][8][8];     // [buf][b][t-octet slot (swizzled)][8 fp16]

    const int tid = threadIdx.x;
    const int blkB = blockIdx.x >> 1;
    const int blkO = blockIdx.x & 1;
    const int b0 = blkB * 64;

    for (int idx = tid; idx < 64 * 13; idx += 1024) {
        int b = idx / 13, j = idx % 13;
        msm[b][j] = (j == 0) ? 1.0f : x[(b0 + b) * 12 + (j - 1)];
    }
    __syncthreads();
    for (int idx = tid; idx < 64 * 78; idx += 1024) {
        int b = idx / 78, q = idx % 78;
        uint32_t m2 = mp[B2 + q];
        msm[b][13 + q] = msm[b][m2 & 0xFFFFu] * msm[b][m2 >> 16];
    }

    const int l = tid & 63, w = tid >> 6;   // 16 waves
    const int lm = l & 15, lg = l >> 4;
    const int wB = w >> 3, wO = w & 7;      // 2 b-halves x 8 o-groups
    const int o_w = blkO * 256 + wO * 32;
    const int bgen = tid & 63;
    const int task = tid >> 6;              // 0..15, 4 t's each
    const int sA = (task >> 1) ^ (bgen & 7);
    const int hOf = (task & 1) * 4;

    f32x4 acc[2][2] = {};
    f16x8 B0[2][2], B1[2][2];               // [os][chunk]

    auto gen = [&](int kt, int buf) {
        int t0 = kt * 64 + task * 4;
        uint4 mq = *(const uint4*)&mp[t0];
        const float* row = msm[bgen];
        uint32_t mqs[4] = {mq.x, mq.y, mq.z, mq.w};
        ushort4 v;
        unsigned short vv[4];
#pragma unroll
        for (int j = 0; j < 4; ++j) {
            float p = row[mqs[j] & 0xFFFFu] * row[mqs[j] >> 16];
            _Float16 h = (_Float16)p;
            vv[j] = __builtin_bit_cast(unsigned short, h);
        }
        v.x = vv[0]; v.y = vv[1]; v.z = vv[2]; v.w = vv[3];
        *(ushort4*)&Ash[buf][bgen][sA][hOf] = v;
    };
    auto loadB = [&](int kt, f16x8 (&B)[2][2]) {
#pragma unroll
        for (int os = 0; os < 2; ++os)
#pragma unroll
            for (int c = 0; c < 2; ++c) {
                int pk = kt * 8 + c * 4 + lg;
                B[os][c] = *(const f16x8*)(Wh + (pk * NO + o_w + os * 16 + lm) * 8);
            }
    };
    auto mfmaR = [&](int cur, f16x8 (&B)[2][2]) {
#pragma unroll
        for (int c = 0; c < 2; ++c) {
            f16x8 a[2];
#pragma unroll
            for (int bs = 0; bs < 2; ++bs) {
                int br = wB * 32 + bs * 16 + lm;
                a[bs] = *(const f16x8*)&Ash[cur][br][(c * 4 + lg) ^ (br & 7)][0];
            }
#pragma unroll
            for (int bs = 0; bs < 2; ++bs)
#pragma unroll
                for (int os = 0; os < 2; ++os)
                    acc[bs][os] = __builtin_amdgcn_mfma_f32_16x16x32_f16(
                        a[bs], B[os][c], acc[bs][os], 0, 0, 0);
        }
    };

    __syncthreads();          // msm ready
    gen(0, 0);
    loadB(0, B0);
    __syncthreads();          // Ash[0] ready

    for (int kt2 = 0; kt2 < 28; kt2 += 2) {
        loadB(kt2 + 1, B1);
        gen(kt2 + 1, 1);
        mfmaR(0, B0);
        __syncthreads();
        loadB(kt2 + 2, B0);   // kt2+2 <= 28 < NKT always
        gen(kt2 + 2, 0);
        mfmaR(1, B1);
        __syncthreads();
    }
    mfmaR(0, B0);             // kt = 28

#pragma unroll
    for (int bs = 0; bs < 2; ++bs)
#pragma unroll
        for (int os = 0; os < 2; ++os) {
            int ob = o_w + os * 16 + lm;
#pragma unroll
            for (int r = 0; r < 4; ++r) {
                int bb = b0 + wB * 32 + bs * 16 + lg * 4 + r;
                out[bb * NO + ob] = acc[bs][os][r];
            }
        }
}

extern "C" void kernel_launch(void* const* d_in, const int* in_sizes, int n_in,
                              void* d_out, int out_size, void* d_ws, size_t ws_size,
                              hipStream_t stream) {
    const float* x  = (const float*)d_in[0];
    const float* w0 = (const float*)d_in[1];
    const float* w1 = (const float*)d_in[2];
    const float* w2 = (const float*)d_in[3];
    const float* w3 = (const float*)d_in[4];
    const float* w4 = (const float*)d_in[5];
    float* out = (float*)d_out;

    uint8_t* ws = (uint8_t*)d_ws;
    uint32_t* mp  = (uint32_t*)ws;                 // 7424 B (pad 8192)
    ushort* cmap2 = (ushort*)(ws + 8192);          // 288 B (pad 512)
    ushort* cmap3 = (ushort*)(ws + 8704);          // 3456 B (pad 3584)
    ushort* cmap4 = (ushort*)(ws + 12288);         // 41472 B (pad 41984)
    ushort* Wh    = (ushort*)(ws + 54272);         // 232*512*8*2 = 1,900,544 B

    pinet_maps<<<96, 256, 0, stream>>>(mp, cmap2, cmap3, cmap4);
    pinet_fold<<<NO, 1024, 0, stream>>>(w0, w1, w2, w3, w4,
                                        cmap2, cmap3, cmap4, Wh);
    pinet_gemm<<<(NB / 64) * 2, 1024, 0, stream>>>(x, Wh, mp, out);
}

// Round 7
// 57.571 us; speedup vs baseline: 15.8407x; 1.7367x over previous
//
#include <hip/hip_runtime.h>
#include <hip/hip_bf16.h>
#include <cstdint>

// PiNet: B=8192, I=12, O=512, DEG=4.
// Symmetry-folded to T = 1820 monomials (padded to 1856 = 29*64).
// R6: fold = stage full weight row in LDS (coalesced) + per-t register gather
// over the permutation orbit (24 reads, x 1/prod(run!)) -- ZERO LDS atomics.

#define NB 8192
#define NI 12
#define NO 512
#define T_TOTAL 1820
#define TPAD 1856          // 29 * 64
#define NKT 29
#define B2 13
#define B3 91
#define B4 455

typedef __attribute__((ext_vector_type(8))) _Float16 f16x8;
typedef __attribute__((ext_vector_type(4))) float f32x4;

__device__ __forceinline__ int H2f(int n) { return n * (n + 1) / 2; }
__device__ __forceinline__ int H3f(int n) { return n * (n + 1) * (n + 2) / 6; }
__device__ __forceinline__ int rank2(int a, int b) {
    int r = 0;
    for (int j = 0; j < a; ++j) r += NI - j;
    return r + (b - a);
}

// ---------- maps: mp (monomial pair table) + tup/rk orbit descriptors ----------
// tup: sorted tuple packed 4b/idx. rk = 1/prod(run-length factorials).
__global__ __launch_bounds__(256) void pinet_maps(
    uint32_t* __restrict__ mp,
    ushort* __restrict__ tup2, float* __restrict__ rk2,
    ushort* __restrict__ tup3, float* __restrict__ rk3,
    ushort* __restrict__ tup4, float* __restrict__ rk4) {
    int id = blockIdx.x * 256 + threadIdx.x;
    if (id < TPAD) {
        int t = id;
        uint32_t v = 0;
        if (t == 0) {
            v = 0;
        } else if (t < B2) {
            v = (uint32_t)t;
        } else if (t < B3) {
            int r = t - B2;
            int a = 0; while (r >= (NI - a)) { r -= (NI - a); ++a; }
            int b = a + r;
            v = (uint32_t)(1 + a) | ((uint32_t)(1 + b) << 16);
        } else if (t < B4) {
            int r = t - B3;
            int a = 0; while (r >= H2f(NI - a)) { r -= H2f(NI - a); ++a; }
            int b = a; while (r >= (NI - b)) { r -= (NI - b); ++b; }
            int c = b + r;
            v = (uint32_t)(13 + rank2(a, b)) | ((uint32_t)(1 + c) << 16);
        } else if (t < T_TOTAL) {
            int r = t - B4;
            int a = 0; while (r >= H3f(NI - a)) { r -= H3f(NI - a); ++a; }
            int b = a; while (r >= H2f(NI - b)) { r -= H2f(NI - b); ++b; }
            int c = b; while (r >= (NI - c)) { r -= (NI - c); ++c; }
            int d = c + r;
            v = (uint32_t)(13 + rank2(a, b)) | ((uint32_t)(13 + rank2(c, d)) << 16);
        }
        mp[t] = v;     // t in [1820,1856): monomial = 1, weight 0
        return;
    }
    id -= TPAD;
    if (id < 1365) {                      // degree 4
        int r = id;
        int a = 0; while (r >= H3f(NI - a)) { r -= H3f(NI - a); ++a; }
        int b = a; while (r >= H2f(NI - b)) { r -= H2f(NI - b); ++b; }
        int c = b; while (r >= (NI - c)) { r -= (NI - c); ++c; }
        int d = c + r;
        tup4[id] = (ushort)(a | (b << 4) | (c << 8) | (d << 12));
        int k = 1, run = 1;
        if (b == a) { ++run; k *= run; } else run = 1;
        if (c == b) { ++run; k *= run; } else run = 1;
        if (d == c) { ++run; k *= run; } else run = 1;
        rk4[id] = 1.0f / (float)k;
        return;
    }
    id -= 1365;
    if (id < 364) {                       // degree 3
        int r = id;
        int a = 0; while (r >= H2f(NI - a)) { r -= H2f(NI - a); ++a; }
        int b = a; while (r >= (NI - b)) { r -= (NI - b); ++b; }
        int c = b + r;
        tup3[id] = (ushort)(a | (b << 4) | (c << 8));
        int k = 1, run = 1;
        if (b == a) { ++run; k *= run; } else run = 1;
        if (c == b) { ++run; k *= run; } else run = 1;
        rk3[id] = 1.0f / (float)k;
        return;
    }
    id -= 364;
    if (id < 78) {                        // degree 2
        int r = id;
        int a = 0; while (r >= (NI - a)) { r -= (NI - a); ++a; }
        int b = a + r;
        tup2[id] = (ushort)(a | (b << 4));
        rk2[id] = (a == b) ? 0.5f : 1.0f;
    }
}

// ---------- fold: stage row in LDS, per-t orbit gather, plain stores ----------
// One block (1024 threads) per o. Output Wh fp16, pack-of-8 layout:
// Wh[((t>>3)*512 + o)*8 + (t&7)].
__global__ __launch_bounds__(1024) void pinet_fold(
    const float* __restrict__ w0, const float* __restrict__ w1,
    const float* __restrict__ w2, const float* __restrict__ w3,
    const float* __restrict__ w4,
    const ushort* __restrict__ tup2, const float* __restrict__ rk2,
    const ushort* __restrict__ tup3, const float* __restrict__ rk3,
    const ushort* __restrict__ tup4, const float* __restrict__ rk4,
    ushort* __restrict__ Wh) {
    __shared__ float sw4[20736];
    __shared__ float sw3[1728];
    __shared__ float sw2[144];
    const int tid = threadIdx.x;
    const int o = blockIdx.x;

    {   // coalesced staging
        const float4* g4 = (const float4*)(w4 + o * 20736);
        float4* s4 = (float4*)sw4;
        for (int i = tid; i < 5184; i += 1024) s4[i] = g4[i];
        if (tid < 432) ((float4*)sw3)[tid] = ((const float4*)(w3 + o * 1728))[tid];
        if (tid < 36)  ((float4*)sw2)[tid] = ((const float4*)(w2 + o * 144))[tid];
    }
    __syncthreads();

#define W4P(p, q, r, s_) sw4[(p) * 1728 + (q) * 144 + (r) * 12 + (s_)]
#define W3P(p, q, r)     sw3[(p) * 144 + (q) * 12 + (r)]
    for (int t = tid; t < TPAD; t += 1024) {
        float s = 0.0f;
        if (t == 0) {
            s = w0[o];
        } else if (t < B2) {
            s = w1[o * 12 + (t - 1)];
        } else if (t < B3) {
            int q = t - B2; int tp = tup2[q];
            int a = tp & 15, b = (tp >> 4) & 15;
            s = (sw2[a * 12 + b] + sw2[b * 12 + a]) * rk2[q];
        } else if (t < B4) {
            int q = t - B3; int tp = tup3[q];
            int a = tp & 15, b = (tp >> 4) & 15, c = (tp >> 8) & 15;
            s = (W3P(a, b, c) + W3P(a, c, b) + W3P(b, a, c) +
                 W3P(b, c, a) + W3P(c, a, b) + W3P(c, b, a)) * rk3[q];
        } else if (t < T_TOTAL) {
            int q = t - B4; int tp = tup4[q];
            int a = tp & 15, b = (tp >> 4) & 15, c = (tp >> 8) & 15, d = (tp >> 12) & 15;
            float s4v =
                W4P(a,b,c,d) + W4P(a,b,d,c) + W4P(a,c,b,d) + W4P(a,c,d,b) +
                W4P(a,d,b,c) + W4P(a,d,c,b) + W4P(b,a,c,d) + W4P(b,a,d,c) +
                W4P(b,c,a,d) + W4P(b,c,d,a) + W4P(b,d,a,c) + W4P(b,d,c,a) +
                W4P(c,a,b,d) + W4P(c,a,d,b) + W4P(c,b,a,d) + W4P(c,b,d,a) +
                W4P(c,d,a,b) + W4P(c,d,b,a) + W4P(d,a,b,c) + W4P(d,a,c,b) +
                W4P(d,b,a,c) + W4P(d,b,c,a) + W4P(d,c,a,b) + W4P(d,c,b,a);
            s = s4v * rk4[q];
        }
        _Float16 h = (_Float16)s;
        Wh[((t >> 3) * NO + o) * 8 + (t & 7)] = __builtin_bit_cast(unsigned short, h);
    }
#undef W4P
#undef W3P
}

// ---------- MFMA GEMM: out[b,o] = sum_t M[t][b] * Wt[t][o], fp16 ----------
// Block: 64 b x 256 o, 1024 threads (16 waves), wave tile 32b x 32o, KT=64.
__global__ __launch_bounds__(1024, 4) void pinet_gemm(
    const float* __restrict__ x, const ushort* __restrict__ Wh,
    const uint32_t* __restrict__ mp, float* __restrict__ out) {
    __shared__ float msm[64][93];           // per-b: {1, x0..x11, 78 deg2}
    __shared__ ushort Ash[2][64][8][8];     // [buf][b][t-octet slot (swizzled)][8 fp16]

    const int tid = threadIdx.x;
    const int blkB = blockIdx.x >> 1;
    const int blkO = blockIdx.x & 1;
    const int b0 = blkB * 64;

    for (int idx = tid; idx < 64 * 13; idx += 1024) {
        int b = idx / 13, j = idx % 13;
        msm[b][j] = (j == 0) ? 1.0f : x[(b0 + b) * 12 + (j - 1)];
    }
    __syncthreads();
    for (int idx = tid; idx < 64 * 78; idx += 1024) {
        int b = idx / 78, q = idx % 78;
        uint32_t m2 = mp[B2 + q];
        msm[b][13 + q] = msm[b][m2 & 0xFFFFu] * msm[b][m2 >> 16];
    }

    const int l = tid & 63, w = tid >> 6;   // 16 waves
    const int lm = l & 15, lg = l >> 4;
    const int wB = w >> 3, wO = w & 7;      // 2 b-halves x 8 o-groups
    const int o_w = blkO * 256 + wO * 32;
    const int bgen = tid & 63;
    const int task = tid >> 6;              // 0..15, 4 t's each
    const int sA = (task >> 1) ^ (bgen & 7);
    const int hOf = (task & 1) * 4;

    f32x4 acc[2][2] = {};
    f16x8 B0[2][2], B1[2][2];               // [os][chunk]

    auto gen = [&](int kt, int buf) {
        int t0 = kt * 64 + task * 4;
        uint4 mq = *(const uint4*)&mp[t0];
        const float* row = msm[bgen];
        uint32_t mqs[4] = {mq.x, mq.y, mq.z, mq.w};
        ushort4 v;
        unsigned short vv[4];
#pragma unroll
        for (int j = 0; j < 4; ++j) {
            float p = row[mqs[j] & 0xFFFFu] * row[mqs[j] >> 16];
            _Float16 h = (_Float16)p;
            vv[j] = __builtin_bit_cast(unsigned short, h);
        }
        v.x = vv[0]; v.y = vv[1]; v.z = vv[2]; v.w = vv[3];
        *(ushort4*)&Ash[buf][bgen][sA][hOf] = v;
    };
    auto loadB = [&](int kt, f16x8 (&B)[2][2]) {
#pragma unroll
        for (int os = 0; os < 2; ++os)
#pragma unroll
            for (int c = 0; c < 2; ++c) {
                int pk = kt * 8 + c * 4 + lg;
                B[os][c] = *(const f16x8*)(Wh + (pk * NO + o_w + os * 16 + lm) * 8);
            }
    };
    auto mfmaR = [&](int cur, f16x8 (&B)[2][2]) {
#pragma unroll
        for (int c = 0; c < 2; ++c) {
            f16x8 a[2];
#pragma unroll
            for (int bs = 0; bs < 2; ++bs) {
                int br = wB * 32 + bs * 16 + lm;
                a[bs] = *(const f16x8*)&Ash[cur][br][(c * 4 + lg) ^ (br & 7)][0];
            }
#pragma unroll
            for (int bs = 0; bs < 2; ++bs)
#pragma unroll
                for (int os = 0; os < 2; ++os)
                    acc[bs][os] = __builtin_amdgcn_mfma_f32_16x16x32_f16(
                        a[bs], B[os][c], acc[bs][os], 0, 0, 0);
        }
    };

    __syncthreads();          // msm ready
    gen(0, 0);
    loadB(0, B0);
    __syncthreads();          // Ash[0] ready

    for (int kt2 = 0; kt2 < 28; kt2 += 2) {
        loadB(kt2 + 1, B1);
        gen(kt2 + 1, 1);
        mfmaR(0, B0);
        __syncthreads();
        loadB(kt2 + 2, B0);   // kt2+2 <= 28 < NKT always
        gen(kt2 + 2, 0);
        mfmaR(1, B1);
        __syncthreads();
    }
    mfmaR(0, B0);             // kt = 28

#pragma unroll
    for (int bs = 0; bs < 2; ++bs)
#pragma unroll
        for (int os = 0; os < 2; ++os) {
            int ob = o_w + os * 16 + lm;
#pragma unroll
            for (int r = 0; r < 4; ++r) {
                int bb = b0 + wB * 32 + bs * 16 + lg * 4 + r;
                out[bb * NO + ob] = acc[bs][os][r];
            }
        }
}

extern "C" void kernel_launch(void* const* d_in, const int* in_sizes, int n_in,
                              void* d_out, int out_size, void* d_ws, size_t ws_size,
                              hipStream_t stream) {
    const float* x  = (const float*)d_in[0];
    const float* w0 = (const float*)d_in[1];
    const float* w1 = (const float*)d_in[2];
    const float* w2 = (const float*)d_in[3];
    const float* w3 = (const float*)d_in[4];
    const float* w4 = (const float*)d_in[5];
    float* out = (float*)d_out;

    uint8_t* ws = (uint8_t*)d_ws;
    uint32_t* mp  = (uint32_t*)ws;                 // 7424 B (pad 8192)
    ushort* tup4  = (ushort*)(ws + 8192);          // 2730 B (pad 3072)
    float*  rk4   = (float*)(ws + 11264);          // 5460 B (pad 5632)
    ushort* tup3  = (ushort*)(ws + 16896);         // 728 B  (pad 1024)
    float*  rk3   = (float*)(ws + 17920);          // 1456 B (pad 1536)
    ushort* tup2  = (ushort*)(ws + 19456);         // 156 B  (pad 512)
    float*  rk2   = (float*)(ws + 19968);          // 312 B  (pad 512)
    ushort* Wh    = (ushort*)(ws + 20480);         // 232*512*8*2 = 1,900,544 B

    pinet_maps<<<15, 256, 0, stream>>>(mp, tup2, rk2, tup3, rk3, tup4, rk4);
    pinet_fold<<<NO, 1024, 0, stream>>>(w0, w1, w2, w3, w4,
                                        tup2, rk2, tup3, rk3, tup4, rk4, Wh);
    pinet_gemm<<<(NB / 64) * 2, 1024, 0, stream>>>(x, Wh, mp, out);
}